// Round 1
// baseline (755.968 us; speedup 1.0000x reference)
//
#include <hip/hip_runtime.h>
#include <hip/hip_bf16.h>

#define Bsz 256
#define Ssz 512
#define Esz 100
#define Hsz 64
#define Gsz 256                       // 4*H
#define SBG (512u * 256u * 256u)      // S*B*G = 33554432 elems per direction

// ---- fast activations (f32) ----
__device__ __forceinline__ float sigf(float x) { return 1.0f / (1.0f + __expf(-x)); }
__device__ __forceinline__ float tanhfast(float x) { return 2.0f / (1.0f + __expf(-2.0f * x)) - 1.0f; }

// ---- bf16 pack/unpack without __hip_bfloat16 ctor issues ----
__device__ __forceinline__ unsigned short f2bf(float f) {
    unsigned int u = __float_as_uint(f);
    unsigned int rnd = 0x7fffu + ((u >> 16) & 1u);   // round-to-nearest-even
    return (unsigned short)((u + rnd) >> 16);
}
__device__ __forceinline__ float bf2f(unsigned short us) {
    return __uint_as_float(((unsigned int)us) << 16);
}

// =====================================================================
// Kernel 1: pregates[dir][s][b][g] = e[b,s,:] @ W_ih[dir].T + (b_ih+b_hh)
//   fp32 compute, bf16 store. Grid: (M/64, 2 dirs). Block: 512.
//   Tile: 64 rows (m = s*256+b) x 256 gates, K chunked 4 x 25.
//   Thread: 8 rows x 4 consecutive gates. W^T in LDS (k-major) so the
//   per-k gate read is one conflict-free float4; A reads are wave-uniform
//   broadcasts.
// =====================================================================
__global__ __launch_bounds__(512) void pregate_gemm(
    const int* __restrict__ x, const float* __restrict__ emb,
    const float* __restrict__ Wihf, const float* __restrict__ Wihb,
    const float* __restrict__ bihf, const float* __restrict__ bhhf,
    const float* __restrict__ bihb, const float* __restrict__ bhhb,
    unsigned short* __restrict__ preg)
{
    __shared__ __align__(16) float WT[25 * 256];   // 25.6 KB, [k_local][gate]
    __shared__ float At[64 * 25];                  // 6.4 KB,  [row][k_local]

    const int t   = threadIdx.x;
    const int mt  = blockIdx.x;
    const int dir = blockIdx.y;
    const float* __restrict__ W   = dir ? Wihb : Wihf;
    const float* __restrict__ bih = dir ? bihb : bihf;
    const float* __restrict__ bhh = dir ? bhhb : bhhf;

    const int tc = t & 63;       // gate group: cols tc*4 .. tc*4+3
    const int tr = t >> 6;       // row group:  rows tr*8 .. tr*8+7

    // gather assignment: 8 threads per row
    const int row   = t >> 3;
    const int part  = t & 7;
    const int m_row = mt * 64 + row;
    const int s_idx = m_row >> 8;       // m = s*256 + b
    const int b_idx = m_row & 255;
    const int xv    = x[b_idx * Ssz + s_idx];
    const float* __restrict__ erow = emb + (size_t)xv * Esz;

    float acc[8][4];
    #pragma unroll
    for (int j = 0; j < 8; ++j) { acc[j][0] = acc[j][1] = acc[j][2] = acc[j][3] = 0.f; }

    for (int kb = 0; kb < 100; kb += 25) {
        __syncthreads();   // protect LDS reuse across chunks
        // stage W^T chunk: [25][256]
        for (int i = t; i < 25 * 256; i += 512) {
            const int kl = i >> 8;
            const int gg = i & 255;
            WT[kl * 256 + gg] = W[gg * Esz + kb + kl];
        }
        // stage A chunk (gathered embedding rows): [64][25]
        for (int j = part; j < 25; j += 8) {
            At[row * 25 + j] = erow[kb + j];
        }
        __syncthreads();

        #pragma unroll
        for (int kl = 0; kl < 25; ++kl) {
            const float4 wv = *(const float4*)&WT[kl * 256 + tc * 4];
            #pragma unroll
            for (int j = 0; j < 8; ++j) {
                const float a = At[(tr * 8 + j) * 25 + kl];   // wave-uniform broadcast
                acc[j][0] = fmaf(a, wv.x, acc[j][0]);
                acc[j][1] = fmaf(a, wv.y, acc[j][1]);
                acc[j][2] = fmaf(a, wv.z, acc[j][2]);
                acc[j][3] = fmaf(a, wv.w, acc[j][3]);
            }
        }
    }

    // epilogue: +bias, bf16 store (8B per row per thread, coalesced)
    const int col0 = tc * 4;
    const float b0 = bih[col0 + 0] + bhh[col0 + 0];
    const float b1 = bih[col0 + 1] + bhh[col0 + 1];
    const float b2 = bih[col0 + 2] + bhh[col0 + 2];
    const float b3 = bih[col0 + 3] + bhh[col0 + 3];
    unsigned short* __restrict__ pd = preg + (size_t)dir * SBG;
    #pragma unroll
    for (int j = 0; j < 8; ++j) {
        const size_t m_j = (size_t)(mt * 64 + tr * 8 + j);
        ushort4 pk;
        pk.x = f2bf(acc[j][0] + b0);
        pk.y = f2bf(acc[j][1] + b1);
        pk.z = f2bf(acc[j][2] + b2);
        pk.w = f2bf(acc[j][3] + b3);
        *reinterpret_cast<ushort4*>(pd + m_j * Gsz + col0) = pk;
    }
}

// =====================================================================
// Kernel 2: per-(sample,direction) LSTM recurrence, all 512 steps in one
//   block. 512 blocks x 256 threads. Thread g owns gate g: W_hh row in
//   64 VGPRs; h in LDS (broadcast reads); c owned by threads 0..63.
//   Pregate for step s+1 is prefetched at the top of step s.
// =====================================================================
__global__ __launch_bounds__(256) void lstm_rec(
    const unsigned short* __restrict__ preg,
    const float* __restrict__ Whhf, const float* __restrict__ Whhb,
    float* __restrict__ hfinal)
{
    __shared__ __align__(16) float h_s[Hsz];
    __shared__ float gate_s[Gsz];

    const int g   = threadIdx.x;
    const int b   = blockIdx.x & 255;
    const int dir = blockIdx.x >> 8;
    const float* __restrict__ Whh = dir ? Whhb : Whhf;

    float w[64];
    #pragma unroll
    for (int k = 0; k < 64; ++k) w[k] = Whh[g * Hsz + k];

    const unsigned short* __restrict__ pd = preg + (size_t)dir * SBG;

    if (g < Hsz) h_s[g] = 0.f;
    float c_ = 0.f, hlast = 0.f;
    __syncthreads();

    const int s0 = dir ? (Ssz - 1) : 0;
    float pg = bf2f(pd[((size_t)s0 * Bsz + b) * Gsz + g]);

    for (int s = 0; s < Ssz; ++s) {
        // prefetch next step's pregate (clamped addr; value unused on last iter)
        int sn = s + 1; if (sn >= Ssz) sn = Ssz - 1;
        const int se = dir ? (Ssz - 1 - sn) : sn;
        const float pg_next = bf2f(pd[((size_t)se * Bsz + b) * Gsz + g]);

        // gate g = pregate + h . W_hh[g,:]
        float acc = pg;
        #pragma unroll
        for (int kk = 0; kk < 16; ++kk) {
            const float4 hv = *(const float4*)&h_s[kk * 4];
            acc = fmaf(hv.x, w[4 * kk + 0], acc);
            acc = fmaf(hv.y, w[4 * kk + 1], acc);
            acc = fmaf(hv.z, w[4 * kk + 2], acc);
            acc = fmaf(hv.w, w[4 * kk + 3], acc);
        }
        // PyTorch gate order i,f,g,o: tanh only for the third quarter
        gate_s[g] = ((g >> 6) == 2) ? tanhfast(acc) : sigf(acc);
        __syncthreads();
        if (g < Hsz) {                     // wave 0 only: c/h update
            const float gi = gate_s[g];
            const float gf = gate_s[Hsz + g];
            const float gg = gate_s[2 * Hsz + g];
            const float go = gate_s[3 * Hsz + g];
            c_    = fmaf(gf, c_, gi * gg);
            hlast = go * tanhfast(c_);
            h_s[g] = hlast;
        }
        __syncthreads();
        pg = pg_next;
    }
    if (g < Hsz) hfinal[((size_t)dir * Bsz + b) * Hsz + g] = hlast;
}

// =====================================================================
// Kernel 3: out[b] = sigmoid([h_f, h_b] . fc_w + fc_b)
// =====================================================================
__global__ void fc_head(const float* __restrict__ hf,
                        const float* __restrict__ fcw, const float* __restrict__ fcb,
                        float* __restrict__ out)
{
    const int b = threadIdx.x;
    float sum = fcb[0];
    const float* h1 = hf + b * Hsz;               // forward
    const float* h2 = hf + Bsz * Hsz + b * Hsz;   // backward
    #pragma unroll 8
    for (int j = 0; j < Hsz; ++j) sum = fmaf(h1[j], fcw[j], sum);
    #pragma unroll 8
    for (int j = 0; j < Hsz; ++j) sum = fmaf(h2[j], fcw[Hsz + j], sum);
    out[b] = 1.0f / (1.0f + __expf(-sum));
}

extern "C" void kernel_launch(void* const* d_in, const int* in_sizes, int n_in,
                              void* d_out, int out_size, void* d_ws, size_t ws_size,
                              hipStream_t stream)
{
    const int*   x    = (const int*)d_in[0];
    const float* emb  = (const float*)d_in[1];
    const float* Wihf = (const float*)d_in[2];
    const float* Whhf = (const float*)d_in[3];
    const float* bihf = (const float*)d_in[4];
    const float* bhhf = (const float*)d_in[5];
    const float* Wihb = (const float*)d_in[6];
    const float* Whhb = (const float*)d_in[7];
    const float* bihb = (const float*)d_in[8];
    const float* bhhb = (const float*)d_in[9];
    const float* fcw  = (const float*)d_in[10];
    const float* fcb  = (const float*)d_in[11];

    // ws layout: [2 x S*B*G bf16 pregates | 2*B*H f32 final hidden]
    unsigned short* preg = (unsigned short*)d_ws;
    float* hf = (float*)((char*)d_ws + (size_t)2 * SBG * sizeof(unsigned short));

    pregate_gemm<<<dim3(2048, 2), 512, 0, stream>>>(x, emb, Wihf, Wihb,
                                                    bihf, bhhf, bihb, bhhb, preg);
    lstm_rec<<<512, 256, 0, stream>>>(preg, Whhf, Whhb, hf);
    fc_head<<<1, 256, 0, stream>>>(hf, fcw, fcb, (float*)d_out);
}